// Round 1
// baseline (748.490 us; speedup 1.0000x reference)
//
#include <hip/hip_runtime.h>
#include <math.h>

// Sizes (fixed by the reference): H=512, NH=8, dh=64, L=2, FF=2048,
// B=16, Fh=num_future_frames=5 (harness always restores 5), Tmem=10,
// N objects=20, P=380 pairs, outputs = 26 pred + 1 existence.
#define HD    512
#define NHEAD 8
#define DHD   64
#define FFD   2048
#define NB    16
#define FH    5
#define TM    10
#define NO    20
#define NP    380
#define NOUTC 27
#define PRED_N 790400   // 16*5*380*26

__device__ __forceinline__ float gelu_f(float v) {
    return 0.5f * v * (1.0f + erff(v * 0.70710678118654752440f));
}

// block=256 reduction of (sum, sumsq) over 512-elem row -> mean, rstd
__device__ __forceinline__ void block_meanvar(float s1, float s2, float* red8,
                                              float& mean, float& rstd) {
    int t = threadIdx.x;
    #pragma unroll
    for (int o = 32; o > 0; o >>= 1) {
        s1 += __shfl_down(s1, o);
        s2 += __shfl_down(s2, o);
    }
    if ((t & 63) == 0) { red8[t >> 6] = s1; red8[4 + (t >> 6)] = s2; }
    __syncthreads();
    float a1 = red8[0] + red8[1] + red8[2] + red8[3];
    float a2 = red8[4] + red8[5] + red8[6] + red8[7];
    mean = a1 * (1.0f / HD);
    float var = a2 * (1.0f / HD) - mean * mean;
    rstd = rsqrtf(var + 1e-5f);
    __syncthreads();
}

// ---------------------------------------------------------------------------
// Prep: x init (blk 0..79), CA K/V both layers (80..399), S/O (400..719),
// M = pe2^T @ [pred;ex]^T and combined bias (720..783).
// ---------------------------------------------------------------------------
__global__ __launch_bounds__(256) void k_prep(
    const float* fq, const float* mem, const float* objf,
    const float* ca_in_w, const float* ca_in_b,
    const float* pe1_w, const float* pe2_w, const float* pe2_b,
    const float* pred_w, const float* pred_b,
    const float* ex_w, const float* ex_b,
    float* x, float* kca, float* vca, float* S, float* O,
    float* M, float* cb)
{
    int blk = blockIdx.x, t = threadIdx.x;
    __shared__ float row_s[HD];

    if (blk < 80) {
        int r = blk, tok = r % FH;
        for (int c = t; c < HD; c += 256) x[r * HD + c] = fq[tok * HD + c];
    } else if (blk < 400) {
        int idx = blk - 80;
        int l = idx / 160, rem = idx % 160;
        int b = rem / TM, u = rem % TM;
        const float* mrow = mem + (b * TM + u) * HD;
        for (int c = t; c < HD; c += 256) row_s[c] = mrow[c];
        __syncthreads();
        const float* W  = ca_in_w + (size_t)l * 3 * HD * HD;
        const float* bb = ca_in_b + l * 3 * HD;
        for (int d = t; d < HD; d += 256) {
            const float* wk = W + (size_t)(HD + d) * HD;
            const float* wv = W + (size_t)(2 * HD + d) * HD;
            float ak = 0.f, av = 0.f;
            for (int c = 0; c < HD; ++c) { ak += row_s[c] * wk[c]; av += row_s[c] * wv[c]; }
            size_t o_ = ((size_t)(l * NB + b) * TM + u) * HD + d;
            kca[o_] = ak + bb[HD + d];
            vca[o_] = av + bb[2 * HD + d];
        }
    } else if (blk < 720) {
        int idx = blk - 400;
        int b = idx / NO, i = idx % NO;
        const float* orow = objf + (b * NO + i) * HD;
        for (int c = t; c < HD; c += 256) row_s[c] = orow[c];
        __syncthreads();
        for (int d = t; d < HD; d += 256) {
            const float* w1 = pe1_w + (size_t)d * 3 * HD;  // pe1_w[d, q], q in [0,1536)
            float as_ = 0.f, ao_ = 0.f;
            for (int c = 0; c < HD; ++c) { as_ += row_s[c] * w1[c]; ao_ += row_s[c] * w1[HD + c]; }
            S[(b * NO + i) * HD + d] = as_;
            O[(b * NO + i) * HD + d] = ao_;
        }
    } else {
        int mb = blk - 720;          // 0..63, each handles 8 d-values
        int dd = t >> 5;             // 0..7
        int k  = t & 31;
        int d  = mb * 8 + dd;
        if (k < NOUTC) {
            const float* wo = (k < 26) ? (pred_w + k * HD) : ex_w;
            float a = 0.f;
            for (int e = 0; e < HD; ++e) a += pe2_w[(size_t)e * HD + d] * wo[e];
            M[d * 28 + k] = a;
        }
        if (mb == 0 && t < NOUTC) {
            const float* wo = (t < 26) ? (pred_w + t * HD) : ex_w;
            float a = (t < 26) ? pred_b[t] : ex_b[0];
            for (int e = 0; e < HD; ++e) a += pe2_b[e] * wo[e];
            cb[t] = a;
        }
    }
}

// ---------------------------------------------------------------------------
// Self-attention, fused QKV proj + softmax + AV per (batch, head). grid=128.
// ---------------------------------------------------------------------------
__global__ __launch_bounds__(256) void k_sa(
    int l, const float* x, const float* in_w, const float* in_b, float* ao)
{
    int b = blockIdx.x >> 3, h = blockIdx.x & 7, t = threadIdx.x;
    __shared__ float xs[FH][HD];
    __shared__ float qkv[3][FH][DHD];
    __shared__ float sc[FH][FH];
    __shared__ float aw[FH][FH];
    for (int i = t; i < FH * HD; i += 256) xs[i / HD][i % HD] = x[b * FH * HD + i];
    __syncthreads();
    if (t < 192) {
        int m = t / DHD, d = t % DHD;
        int row = m * HD + h * DHD + d;
        const float* w = in_w + ((size_t)l * 3 * HD + row) * HD;
        float a0 = 0, a1 = 0, a2 = 0, a3 = 0, a4 = 0;
        for (int c = 0; c < HD; ++c) {
            float wv = w[c];
            a0 += xs[0][c] * wv; a1 += xs[1][c] * wv; a2 += xs[2][c] * wv;
            a3 += xs[3][c] * wv; a4 += xs[4][c] * wv;
        }
        float bb = in_b[l * 3 * HD + row];
        qkv[m][0][d] = a0 + bb; qkv[m][1][d] = a1 + bb; qkv[m][2][d] = a2 + bb;
        qkv[m][3][d] = a3 + bb; qkv[m][4][d] = a4 + bb;
    }
    __syncthreads();
    if (t < 25) {
        int tq = t / 5, tu = t % 5;
        float s = 0;
        for (int d = 0; d < DHD; ++d) s += qkv[0][tq][d] * qkv[1][tu][d];
        sc[tq][tu] = s * 0.125f;                // 1/sqrt(64)
    }
    __syncthreads();
    if (t < 5) {
        float mx = -1e30f;
        for (int u = 0; u < 5; ++u) mx = fmaxf(mx, sc[t][u]);
        float e[5], sm = 0;
        for (int u = 0; u < 5; ++u) { e[u] = expf(sc[t][u] - mx); sm += e[u]; }
        for (int u = 0; u < 5; ++u) aw[t][u] = e[u] / sm;
    }
    __syncthreads();
    if (t < DHD) {
        for (int tok = 0; tok < FH; ++tok) {
            float o = 0;
            for (int u = 0; u < 5; ++u) o += aw[tok][u] * qkv[2][u][t];
            ao[(b * FH + tok) * HD + h * DHD + t] = o;
        }
    }
}

// ---------------------------------------------------------------------------
// Cross-attention: Q proj (K/V precomputed) + softmax + AV. grid=128.
// ---------------------------------------------------------------------------
__global__ __launch_bounds__(256) void k_ca(
    int l, const float* x, const float* in_w, const float* in_b,
    const float* kca, const float* vca, float* ao)
{
    int b = blockIdx.x >> 3, h = blockIdx.x & 7, t = threadIdx.x;
    __shared__ float xs[FH][HD];
    __shared__ float q[FH][DHD];
    __shared__ float kl[TM][DHD];
    __shared__ float vl[TM][DHD];
    __shared__ float sc[FH][TM];
    __shared__ float aw[FH][TM];
    for (int i = t; i < FH * HD; i += 256) xs[i / HD][i % HD] = x[b * FH * HD + i];
    for (int i = t; i < TM * DHD; i += 256) {
        int u = i / DHD, d = i % DHD;
        size_t o_ = ((size_t)(l * NB + b) * TM + u) * HD + h * DHD + d;
        kl[u][d] = kca[o_];
        vl[u][d] = vca[o_];
    }
    __syncthreads();
    if (t < DHD) {
        int d = t;
        const float* w = in_w + ((size_t)l * 3 * HD + h * DHD + d) * HD;
        float a0 = 0, a1 = 0, a2 = 0, a3 = 0, a4 = 0;
        for (int c = 0; c < HD; ++c) {
            float wv = w[c];
            a0 += xs[0][c] * wv; a1 += xs[1][c] * wv; a2 += xs[2][c] * wv;
            a3 += xs[3][c] * wv; a4 += xs[4][c] * wv;
        }
        float bb = in_b[l * 3 * HD + h * DHD + d];
        q[0][d] = a0 + bb; q[1][d] = a1 + bb; q[2][d] = a2 + bb;
        q[3][d] = a3 + bb; q[4][d] = a4 + bb;
    }
    __syncthreads();
    if (t < 50) {
        int tq = t / TM, tu = t % TM;
        float s = 0;
        for (int d = 0; d < DHD; ++d) s += q[tq][d] * kl[tu][d];
        sc[tq][tu] = s * 0.125f;
    }
    __syncthreads();
    if (t < 5) {
        float mx = -1e30f;
        for (int u = 0; u < TM; ++u) mx = fmaxf(mx, sc[t][u]);
        float e[TM], sm = 0;
        for (int u = 0; u < TM; ++u) { e[u] = expf(sc[t][u] - mx); sm += e[u]; }
        for (int u = 0; u < TM; ++u) aw[t][u] = e[u] / sm;
    }
    __syncthreads();
    if (t < DHD) {
        for (int tok = 0; tok < FH; ++tok) {
            float o = 0;
            for (int u = 0; u < TM; ++u) o += aw[tok][u] * vl[u][t];
            ao[(b * FH + tok) * HD + h * DHD + t] = o;
        }
    }
}

// ---------------------------------------------------------------------------
// out-proj + residual + LayerNorm, one row per block. grid=80.
// x[r] = LN(x[r] + ao[r] @ W^T + bo) with (lw, lb).
// ---------------------------------------------------------------------------
__global__ __launch_bounds__(256) void k_projln(
    const float* ao, const float* W, const float* bo,
    const float* lw, const float* lb, float* x)
{
    int r = blockIdx.x, t = threadIdx.x;
    __shared__ float as_[HD];
    __shared__ float red8[8];
    for (int c = t; c < HD; c += 256) as_[c] = ao[r * HD + c];
    __syncthreads();
    float y[2];
    #pragma unroll
    for (int ci = 0; ci < 2; ++ci) {
        int c = t + ci * 256;
        const float* w = W + (size_t)c * HD;
        float a = 0;
        for (int k = 0; k < HD; ++k) a += as_[k] * w[k];
        y[ci] = a + bo[c] + x[r * HD + c];
    }
    float mean, rstd;
    block_meanvar(y[0] + y[1], y[0] * y[0] + y[1] * y[1], red8, mean, rstd);
    #pragma unroll
    for (int ci = 0; ci < 2; ++ci) {
        int c = t + ci * 256;
        x[r * HD + c] = (y[ci] - mean) * rstd * lw[c] + lb[c];
    }
}

// residual + LN only (FF2 path): x[r] = LN(x[r] + yt[r] + bo)
__global__ __launch_bounds__(256) void k_resln(
    const float* yt, const float* bo,
    const float* lw, const float* lb, float* x)
{
    int r = blockIdx.x, t = threadIdx.x;
    __shared__ float red8[8];
    float y[2];
    #pragma unroll
    for (int ci = 0; ci < 2; ++ci) {
        int c = t + ci * 256;
        y[ci] = x[r * HD + c] + yt[r * HD + c] + bo[c];
    }
    float mean, rstd;
    block_meanvar(y[0] + y[1], y[0] * y[0] + y[1] * y[1], red8, mean, rstd);
    #pragma unroll
    for (int ci = 0; ci < 2; ++ci) {
        int c = t + ci * 256;
        x[r * HD + c] = (y[ci] - mean) * rstd * lw[c] + lb[c];
    }
}

// ---------------------------------------------------------------------------
// FF1: hff = gelu(x @ W1^T + b1). grid = 16 b x 8 coltiles(256).
// ---------------------------------------------------------------------------
__global__ __launch_bounds__(256) void k_ff1(
    int l, const float* x, const float* W, const float* bb, float* hff)
{
    int b = blockIdx.x >> 3, ct = blockIdx.x & 7, t = threadIdx.x;
    __shared__ float xs[FH][HD];
    for (int i = t; i < FH * HD; i += 256) xs[i / HD][i % HD] = x[b * FH * HD + i];
    __syncthreads();
    int c = ct * 256 + t;
    const float* w = W + ((size_t)l * FFD + c) * HD;
    float a0 = 0, a1 = 0, a2 = 0, a3 = 0, a4 = 0;
    for (int k = 0; k < HD; ++k) {
        float wv = w[k];
        a0 += xs[0][k] * wv; a1 += xs[1][k] * wv; a2 += xs[2][k] * wv;
        a3 += xs[3][k] * wv; a4 += xs[4][k] * wv;
    }
    float bc = bb[l * FFD + c];
    hff[(b * FH + 0) * FFD + c] = gelu_f(a0 + bc);
    hff[(b * FH + 1) * FFD + c] = gelu_f(a1 + bc);
    hff[(b * FH + 2) * FFD + c] = gelu_f(a2 + bc);
    hff[(b * FH + 3) * FFD + c] = gelu_f(a3 + bc);
    hff[(b * FH + 4) * FFD + c] = gelu_f(a4 + bc);
}

// ---------------------------------------------------------------------------
// FF2 (no bias/residual/LN here): yt = hff @ W2^T.
// grid = 16 b x 8 coltiles(64), 4-way K-split across waves.
// ---------------------------------------------------------------------------
__global__ __launch_bounds__(256) void k_ff2(
    int l, const float* hff, const float* W, float* yt)
{
    int b = blockIdx.x >> 3, ct = blockIdx.x & 7, t = threadIdx.x;
    __shared__ float hs[FH * FFD];                 // 40 KiB
    for (int i = t; i < FH * FFD; i += 256) hs[i] = hff[b * FH * FFD + i];
    __syncthreads();
    int cl = t & 63, ks = t >> 6;
    int c = ct * 64 + cl;
    const float* w  = W + ((size_t)l * HD + c) * FFD + ks * 512;
    const float* h0 = hs + ks * 512;
    float a0 = 0, a1 = 0, a2 = 0, a3 = 0, a4 = 0;
    for (int k = 0; k < 512; ++k) {
        float wv = w[k];
        a0 += h0[0 * FFD + k] * wv; a1 += h0[1 * FFD + k] * wv;
        a2 += h0[2 * FFD + k] * wv; a3 += h0[3 * FFD + k] * wv;
        a4 += h0[4 * FFD + k] * wv;
    }
    __syncthreads();                               // done reading hs
    float* red = hs;                               // reuse: [ks][cl][tok]
    red[(ks * 64 + cl) * FH + 0] = a0;
    red[(ks * 64 + cl) * FH + 1] = a1;
    red[(ks * 64 + cl) * FH + 2] = a2;
    red[(ks * 64 + cl) * FH + 3] = a3;
    red[(ks * 64 + cl) * FH + 4] = a4;
    __syncthreads();
    for (int idx = t; idx < 64 * FH; idx += 256) {
        int c2 = idx / FH, tok = idx % FH;
        float s = red[(0 * 64 + c2) * FH + tok] + red[(1 * 64 + c2) * FH + tok]
                + red[(2 * 64 + c2) * FH + tok] + red[(3 * 64 + c2) * FH + tok];
        yt[(b * FH + tok) * HD + ct * 64 + c2] = s;
    }
}

// ---------------------------------------------------------------------------
// Final LN + ctx projection: C[r] = LN(x[r]) @ pe1_w[:,1024:1536]^T + pe1_b
// ---------------------------------------------------------------------------
__global__ __launch_bounds__(256) void k_normc(
    const float* x, const float* nw, const float* nb,
    const float* pe1_w, const float* pe1_b, float* C)
{
    int r = blockIdx.x, t = threadIdx.x;
    __shared__ float ctx[HD];
    __shared__ float red8[8];
    float v0 = x[r * HD + t], v1 = x[r * HD + t + 256];
    float mean, rstd;
    block_meanvar(v0 + v1, v0 * v0 + v1 * v1, red8, mean, rstd);
    ctx[t]       = (v0 - mean) * rstd * nw[t]       + nb[t];
    ctx[t + 256] = (v1 - mean) * rstd * nw[t + 256] + nb[t + 256];
    __syncthreads();
    #pragma unroll
    for (int ci = 0; ci < 2; ++ci) {
        int d = t + ci * 256;
        const float* w = pe1_w + (size_t)d * 3 * HD + 2 * HD;
        float a = 0;
        for (int c = 0; c < HD; ++c) a += ctx[c] * w[c];
        C[r * HD + d] = a + pe1_b[d];
    }
}

// ---------------------------------------------------------------------------
// Pair head: out[r,k] = gelu(S[b,i]+O[b,j]+C[b,f]) . M[:,k] + cb[k]
// grid = 16*5*6 blocks; block = 64 rows x 4-way K-split.
// ---------------------------------------------------------------------------
__global__ __launch_bounds__(256) void k_pair(
    const float* S, const float* O, const float* C,
    const float* M, const float* cb, float* out)
{
    int blk = blockIdx.x;
    int bf = blk / 6, pt = blk % 6;
    int b = bf / FH, f = bf % FH;
    int t = threadIdx.x;
    int rl = t & 63, ks = t >> 6;
    int p = pt * 64 + rl;
    bool act = (p < NP);
    int i = 0, j = 0;
    if (act) { i = p / 19; int j0 = p % 19; j = j0 + (j0 >= i ? 1 : 0); }
    const float* Sr = S + (b * NO + i) * HD;
    const float* Or = O + (b * NO + j) * HD;
    const float* Cr = C + (b * FH + f) * HD;
    float acc[NOUTC];
    #pragma unroll
    for (int k = 0; k < NOUTC; ++k) acc[k] = 0.f;
    if (act) {
        int d0 = ks * 128;
        for (int dd = 0; dd < 128; dd += 4) {
            int d = d0 + dd;
            float4 sv = *(const float4*)(Sr + d);
            float4 ov = *(const float4*)(Or + d);
            float4 cv = *(const float4*)(Cr + d);
            float g0 = gelu_f(sv.x + ov.x + cv.x);
            float g1 = gelu_f(sv.y + ov.y + cv.y);
            float g2 = gelu_f(sv.z + ov.z + cv.z);
            float g3 = gelu_f(sv.w + ov.w + cv.w);
            const float* m0 = M + d * 28;          // uniform across lanes -> s_load
            #pragma unroll
            for (int k = 0; k < NOUTC; ++k)
                acc[k] += g0 * m0[k] + g1 * m0[28 + k] + g2 * m0[56 + k] + g3 * m0[84 + k];
        }
    }
    __shared__ float red[4][64][NOUTC];            // 27.6 KiB
    #pragma unroll
    for (int k = 0; k < NOUTC; ++k) red[ks][rl][k] = acc[k];
    __syncthreads();
    int pbase = (b * FH + f) * NP;
    for (int idx = t; idx < 64 * NOUTC; idx += 256) {
        int r2 = idx / NOUTC, k = idx % NOUTC;
        int p2 = pt * 64 + r2;
        if (p2 >= NP) continue;
        float s = red[0][r2][k] + red[1][r2][k] + red[2][r2][k] + red[3][r2][k] + cb[k];
        if (k < 26) out[(size_t)(pbase + p2) * 26 + k] = s;
        else        out[PRED_N + pbase + p2] = s;
    }
}

// ---------------------------------------------------------------------------
extern "C" void kernel_launch(void* const* d_in, const int* in_sizes, int n_in,
                              void* d_out, int out_size, void* d_ws, size_t ws_size,
                              hipStream_t stream) {
    const float* temporal = (const float*)d_in[0];
    const float* objf     = (const float*)d_in[1];
    const float* fq       = (const float*)d_in[2];
    const float* sa_in_w  = (const float*)d_in[3];
    const float* sa_in_b  = (const float*)d_in[4];
    const float* sa_out_w = (const float*)d_in[5];
    const float* sa_out_b = (const float*)d_in[6];
    const float* ca_in_w  = (const float*)d_in[7];
    const float* ca_in_b  = (const float*)d_in[8];
    const float* ca_out_w = (const float*)d_in[9];
    const float* ca_out_b = (const float*)d_in[10];
    const float* ff1_w    = (const float*)d_in[11];
    const float* ff1_b    = (const float*)d_in[12];
    const float* ff2_w    = (const float*)d_in[13];
    const float* ff2_b    = (const float*)d_in[14];
    const float* n1_w     = (const float*)d_in[15];
    const float* n1_b     = (const float*)d_in[16];
    const float* n2_w     = (const float*)d_in[17];
    const float* n2_b     = (const float*)d_in[18];
    const float* n3_w     = (const float*)d_in[19];
    const float* n3_b     = (const float*)d_in[20];
    const float* norm_w   = (const float*)d_in[21];
    const float* norm_b   = (const float*)d_in[22];
    const float* pe1_w    = (const float*)d_in[23];
    const float* pe1_b    = (const float*)d_in[24];
    const float* pe2_w    = (const float*)d_in[25];
    const float* pe2_b    = (const float*)d_in[26];
    const float* pred_w   = (const float*)d_in[27];
    const float* pred_b   = (const float*)d_in[28];
    const float* ex_w     = (const float*)d_in[29];
    const float* ex_b     = (const float*)d_in[30];
    // d_in[31] = num_future_frames; always 5 for this harness (out_size depends on it).

    float* ws  = (float*)d_ws;
    float* x   = ws;                 // 16*5*512        = 40960
    float* ao  = ws + 40960;         // 16*5*512        = 40960
    float* kca = ws + 81920;         // 2*16*10*512     = 163840
    float* vca = ws + 245760;        // 163840
    float* S   = ws + 409600;        // 16*20*512       = 163840
    float* O   = ws + 573440;        // 163840
    float* Cc  = ws + 737280;        // 16*5*512        = 40960
    float* M   = ws + 778240;        // 512*28          = 14336
    float* cbp = ws + 792576;        // 32
    float* hff = ws + 792608;        // 16*5*2048       = 163840
    float* yt  = ws + 956448;        // 40960  (total ~3.99 MB)
    float* out = (float*)d_out;

    k_prep<<<784, 256, 0, stream>>>(fq, temporal, objf, ca_in_w, ca_in_b,
                                    pe1_w, pe2_w, pe2_b, pred_w, pred_b, ex_w, ex_b,
                                    x, kca, vca, S, O, M, cbp);
    for (int l = 0; l < 2; ++l) {
        k_sa<<<128, 256, 0, stream>>>(l, x, sa_in_w, sa_in_b, ao);
        k_projln<<<80, 256, 0, stream>>>(ao, sa_out_w + (size_t)l * HD * HD,
                                         sa_out_b + l * HD, n1_w + l * HD, n1_b + l * HD, x);
        k_ca<<<128, 256, 0, stream>>>(l, x, ca_in_w, ca_in_b, kca, vca, ao);
        k_projln<<<80, 256, 0, stream>>>(ao, ca_out_w + (size_t)l * HD * HD,
                                         ca_out_b + l * HD, n2_w + l * HD, n2_b + l * HD, x);
        k_ff1<<<128, 256, 0, stream>>>(l, x, ff1_w, ff1_b, hff);
        k_ff2<<<128, 256, 0, stream>>>(l, hff, ff2_w, yt);
        k_resln<<<80, 256, 0, stream>>>(yt, ff2_b + l * HD, n3_w + l * HD, n3_b + l * HD, x);
    }
    k_normc<<<80, 256, 0, stream>>>(x, norm_w, norm_b, pe1_w, pe1_b, Cc);
    k_pair<<<480, 256, 0, stream>>>(S, O, Cc, M, cbp, out);
}

// Round 3
// 546.096 us; speedup vs baseline: 1.3706x; 1.3706x over previous
//
#include <hip/hip_runtime.h>
#include <math.h>

// Problem sizes (fixed): H=512, heads=8, dh=64, L=2, FF=2048, B=16,
// Fh=5, Tmem=10, Nobj=20, Pairs=380, out = 26 pred + 1 ex.
#define HD 512
#define FFD 2048
#define NBATCH 16
#define FH 5
#define TM 10
#define NO 20
#define NP 380
#define NOUTC 27
#define PRED_N 790400   // 16*5*380*26

__device__ __forceinline__ float gelu_f(float v) {
    return 0.5f * v * (1.0f + erff(v * 0.70710678118654752440f));
}

// block=256: reduce (sum,sumsq) of a 512-wide row -> mean, rstd
__device__ __forceinline__ void block_meanvar(float s1, float s2, float* red8,
                                              float& mean, float& rstd) {
    int t = threadIdx.x;
    #pragma unroll
    for (int o = 32; o > 0; o >>= 1) {
        s1 += __shfl_down(s1, o);
        s2 += __shfl_down(s2, o);
    }
    if ((t & 63) == 0) { red8[t >> 6] = s1; red8[4 + (t >> 6)] = s2; }
    __syncthreads();
    float a1 = red8[0] + red8[1] + red8[2] + red8[3];
    float a2 = red8[4] + red8[5] + red8[6] + red8[7];
    mean = a1 * (1.0f / HD);
    float var = a2 * (1.0f / HD) - mean * mean;
    rstd = rsqrtf(var + 1e-5f);
    __syncthreads();
}

// ---------------------------------------------------------------------------
// Generic tiled GEMM: Y[z][r][n] (+= over k in z-chunk) = X[r][k] * W[n][k]
// Block tile 16 rows x 128 cols, K-chunk 64. Thread: 2 rows x 4 cols
// (cols c, c+32, c+64, c+96; c = t&31). W staged transposed in LDS stride 129
// -> bank=(k+c)%32: stores 2-way (free), compute reads conflict-free.
// xmode: 0 = plain; 1 = gelu(p0 + p0[xpstride] + xb) (FF1 combine); 2 = row%5.
// NOTE: W must have at least (nb_max+128) rows of ldw floats — callers are
// responsible (pe1_w has only 512 rows: S and O are SEPARATE launches).
// ---------------------------------------------------------------------------
__global__ __launch_bounds__(256) void k_gemm(
    const float* __restrict__ X, int ldx, int xmode,
    const float* __restrict__ xb, int xpstride,
    const float* __restrict__ W, int ldw,
    float* __restrict__ Y, int N, int Klen, int zystride)
{
    __shared__ float Wt[64 * 129];   // 33 KB
    __shared__ float Xl[16 * 64];    // 4 KB
    int t = threadIdx.x;
    int nb = blockIdx.x * 128;
    int r0 = blockIdx.y * 16;
    int z  = blockIdx.z;
    int kbase = z * Klen;
    int c  = t & 31;        // compute col base
    int rg = t >> 5;        // compute row group (2 rows each)
    int sc = t >> 4;        // staging row 0..15
    int q  = t & 15;        // staging k-float4 idx

    float a00 = 0, a01 = 0, a02 = 0, a03 = 0;
    float a10 = 0, a11 = 0, a12 = 0, a13 = 0;

    for (int kc = 0; kc < Klen; kc += 64) {
        int kg = kbase + kc;
        // ---- stage X tile (16 x 64) ----
        {
            float4 xv;
            if (xmode == 0) {
                xv = *(const float4*)(X + (size_t)(r0 + sc) * ldx + kg + q * 4);
            } else if (xmode == 2) {
                xv = *(const float4*)(X + (size_t)((r0 + sc) % FH) * ldx + kg + q * 4);
            } else {
                const float* p0 = X + (size_t)(r0 + sc) * ldx + kg + q * 4;
                float4 a = *(const float4*)p0;
                float4 b = *(const float4*)(p0 + xpstride);
                float4 bi = *(const float4*)(xb + kg + q * 4);
                xv.x = gelu_f(a.x + b.x + bi.x);
                xv.y = gelu_f(a.y + b.y + bi.y);
                xv.z = gelu_f(a.z + b.z + bi.z);
                xv.w = gelu_f(a.w + b.w + bi.w);
            }
            *(float4*)&Xl[sc * 64 + q * 4] = xv;
        }
        // ---- stage W tile (128 cols x 64 k), transposed into Wt[k][129] ----
        #pragma unroll
        for (int p = 0; p < 8; ++p) {
            int cc = sc + p * 16;
            float4 wv = *(const float4*)(W + (size_t)(nb + cc) * ldw + kg + q * 4);
            Wt[(q * 4 + 0) * 129 + cc] = wv.x;
            Wt[(q * 4 + 1) * 129 + cc] = wv.y;
            Wt[(q * 4 + 2) * 129 + cc] = wv.z;
            Wt[(q * 4 + 3) * 129 + cc] = wv.w;
        }
        __syncthreads();
        // ---- compute ----
        const float* xr0 = &Xl[(rg * 2 + 0) * 64];
        const float* xr1 = &Xl[(rg * 2 + 1) * 64];
        #pragma unroll
        for (int k4 = 0; k4 < 16; ++k4) {
            float4 x0 = *(const float4*)(xr0 + k4 * 4);
            float4 x1 = *(const float4*)(xr1 + k4 * 4);
            const float* x0p = (const float*)&x0;
            const float* x1p = (const float*)&x1;
            #pragma unroll
            for (int i = 0; i < 4; ++i) {
                const float* wrow = &Wt[(k4 * 4 + i) * 129 + c];
                float w0 = wrow[0], w1 = wrow[32], w2 = wrow[64], w3 = wrow[96];
                float xi0 = x0p[i], xi1 = x1p[i];
                a00 = fmaf(xi0, w0, a00); a01 = fmaf(xi0, w1, a01);
                a02 = fmaf(xi0, w2, a02); a03 = fmaf(xi0, w3, a03);
                a10 = fmaf(xi1, w0, a10); a11 = fmaf(xi1, w1, a11);
                a12 = fmaf(xi1, w2, a12); a13 = fmaf(xi1, w3, a13);
            }
        }
        __syncthreads();
    }
    float* yr = Y + (size_t)z * zystride + (size_t)(r0 + rg * 2) * N + nb + c;
    yr[0] = a00; yr[32] = a01; yr[64] = a02; yr[96] = a03;
    yr += N;
    yr[0] = a10; yr[32] = a11; yr[64] = a12; yr[96] = a13;
}

// ---------------------------------------------------------------------------
// Self-attention core: QKV partials (2 k-splits) + bias, softmax, AV.
// grid = 16*8 (b,h).
// ---------------------------------------------------------------------------
__global__ __launch_bounds__(256) void k_attn_sa(
    int l, const float* __restrict__ qkvp, int zstr,
    const float* __restrict__ in_b, float* __restrict__ ao)
{
    int b = blockIdx.x >> 3, h = blockIdx.x & 7, t = threadIdx.x;
    __shared__ float qkv[3][FH][64];
    __shared__ float sc[FH][FH];
    __shared__ float aw[FH][FH];
    for (int idx = t; idx < 3 * FH * 64; idx += 256) {
        int m = idx / (FH * 64);
        int rem = idx % (FH * 64);
        int tok = rem >> 6, d = rem & 63;
        int col = m * HD + h * 64 + d;
        size_t o_ = (size_t)(b * FH + tok) * 1536 + col;
        qkv[m][tok][d] = qkvp[o_] + qkvp[zstr + o_] + in_b[l * 1536 + col];
    }
    __syncthreads();
    if (t < 25) {
        int tq = t / 5, tu = t % 5;
        float s = 0;
        for (int d = 0; d < 64; ++d) s += qkv[0][tq][d] * qkv[1][tu][d];
        sc[tq][tu] = s * 0.125f;
    }
    __syncthreads();
    if (t < 5) {
        float mx = -1e30f;
        for (int u = 0; u < 5; ++u) mx = fmaxf(mx, sc[t][u]);
        float e[5], sm = 0;
        for (int u = 0; u < 5; ++u) { e[u] = expf(sc[t][u] - mx); sm += e[u]; }
        for (int u = 0; u < 5; ++u) aw[t][u] = e[u] / sm;
    }
    __syncthreads();
    if (t < 64) {
        for (int tok = 0; tok < FH; ++tok) {
            float o = 0;
            for (int u = 0; u < 5; ++u) o += aw[tok][u] * qkv[2][u][t];
            ao[(size_t)(b * FH + tok) * HD + h * 64 + t] = o;
        }
    }
}

// ---------------------------------------------------------------------------
// Cross-attention core: Q partials (2) + KV partials (2) + biases.
// kvl holds the CURRENT layer only: [z][b*TM+u][1024] (K | V).
// ---------------------------------------------------------------------------
__global__ __launch_bounds__(256) void k_attn_ca(
    int l, const float* __restrict__ qp, int qzstr,
    const float* __restrict__ kvl, int kvzstr,
    const float* __restrict__ ca_in_b, float* __restrict__ ao)
{
    int b = blockIdx.x >> 3, h = blockIdx.x & 7, t = threadIdx.x;
    __shared__ float q[FH][64];
    __shared__ float kl[TM][64];
    __shared__ float vl[TM][64];
    __shared__ float sc[FH][TM];
    __shared__ float aw[FH][TM];
    const float* bb = ca_in_b + l * 1536;
    for (int idx = t; idx < FH * 64; idx += 256) {
        int tok = idx >> 6, d = idx & 63;
        size_t o_ = (size_t)(b * FH + tok) * HD + h * 64 + d;
        q[tok][d] = qp[o_] + qp[qzstr + o_] + bb[h * 64 + d];
    }
    for (int idx = t; idx < TM * 64; idx += 256) {
        int u = idx >> 6, d = idx & 63;
        size_t o_ = (size_t)(b * TM + u) * 1024 + h * 64 + d;
        kl[u][d] = kvl[o_] + kvl[kvzstr + o_] + bb[HD + h * 64 + d];
        vl[u][d] = kvl[o_ + 512] + kvl[kvzstr + o_ + 512] + bb[2 * HD + h * 64 + d];
    }
    __syncthreads();
    if (t < 50) {
        int tq = t / TM, tu = t % TM;
        float s = 0;
        for (int d = 0; d < 64; ++d) s += q[tq][d] * kl[tu][d];
        sc[tq][tu] = s * 0.125f;
    }
    __syncthreads();
    if (t < 5) {
        float mx = -1e30f;
        for (int u = 0; u < TM; ++u) mx = fmaxf(mx, sc[t][u]);
        float e[TM], sm = 0;
        for (int u = 0; u < TM; ++u) { e[u] = expf(sc[t][u] - mx); sm += e[u]; }
        for (int u = 0; u < TM; ++u) aw[t][u] = e[u] / sm;
    }
    __syncthreads();
    if (t < 64) {
        for (int tok = 0; tok < FH; ++tok) {
            float o = 0;
            for (int u = 0; u < TM; ++u) o += aw[tok][u] * vl[u][t];
            ao[(size_t)(b * FH + tok) * HD + h * 64 + t] = o;
        }
    }
}

// ---------------------------------------------------------------------------
// residual + sum(np partials) + bias + LN; optional second LN (final norm).
// grid = 80 rows.
// ---------------------------------------------------------------------------
__global__ __launch_bounds__(256) void k_resln(
    const float* __restrict__ parts, int np, int zstride,
    const float* __restrict__ bo,
    const float* __restrict__ lw, const float* __restrict__ lb,
    const float* __restrict__ xsrc, int xmod,
    float* __restrict__ x,
    int fin, const float* __restrict__ fw, const float* __restrict__ fb,
    float* __restrict__ xn)
{
    int r = blockIdx.x, t = threadIdx.x;
    __shared__ float red8[8];
    int rs = xmod ? (r % xmod) : r;
    float y[2];
    #pragma unroll
    for (int ci = 0; ci < 2; ++ci) {
        int cx = t + ci * 256;
        float a = xsrc[(size_t)rs * HD + cx] + bo[cx];
        for (int z = 0; z < np; ++z)
            a += parts[(size_t)z * zstride + (size_t)r * HD + cx];
        y[ci] = a;
    }
    float mean, rstd;
    block_meanvar(y[0] + y[1], y[0] * y[0] + y[1] * y[1], red8, mean, rstd);
    float o[2];
    #pragma unroll
    for (int ci = 0; ci < 2; ++ci) {
        int cx = t + ci * 256;
        o[ci] = (y[ci] - mean) * rstd * lw[cx] + lb[cx];
        x[(size_t)r * HD + cx] = o[ci];
    }
    if (fin) {
        float m2, rs2;
        block_meanvar(o[0] + o[1], o[0] * o[0] + o[1] * o[1], red8, m2, rs2);
        #pragma unroll
        for (int ci = 0; ci < 2; ++ci) {
            int cx = t + ci * 256;
            xn[(size_t)r * HD + cx] = (o[ci] - m2) * rs2 * fw[cx] + fb[cx];
        }
    }
}

// ---------------------------------------------------------------------------
// M partials: Mp[ec][d][28], lanes over d (coalesced pe2_w rows), pred_w via
// uniform scalar loads. grid = 16 (2 dblk x 8 e-chunks).
// ---------------------------------------------------------------------------
__global__ __launch_bounds__(256) void k_mpart(
    const float* __restrict__ pe2_w, const float* __restrict__ pred_w,
    const float* __restrict__ ex_w, float* __restrict__ Mp)
{
    int dblk = blockIdx.x & 1, ec = blockIdx.x >> 1;
    int d = dblk * 256 + threadIdx.x;
    float acc[NOUTC];
    #pragma unroll
    for (int k = 0; k < NOUTC; ++k) acc[k] = 0.f;
    for (int e = ec * 64; e < ec * 64 + 64; ++e) {
        float wv = pe2_w[(size_t)e * HD + d];
        #pragma unroll
        for (int k = 0; k < 26; ++k) acc[k] = fmaf(wv, pred_w[k * HD + e], acc[k]);
        acc[26] = fmaf(wv, ex_w[e], acc[26]);
    }
    float* mp = Mp + ((size_t)ec * HD + d) * 28;
    #pragma unroll
    for (int k = 0; k < NOUTC; ++k) mp[k] = acc[k];
}

// combine M partials (blocks 0,1) + combined bias cb (block 2)
__global__ __launch_bounds__(256) void k_mcomb(
    const float* __restrict__ Mp, const float* __restrict__ pe2_b,
    const float* __restrict__ pred_w, const float* __restrict__ pred_b,
    const float* __restrict__ ex_w, const float* __restrict__ ex_b,
    float* __restrict__ M2, float* __restrict__ cb)
{
    int blk = blockIdx.x, t = threadIdx.x;
    if (blk < 2) {
        for (int idx = t; idx < 7168; idx += 256) {
            int gi = blk * 7168 + idx;
            float s = 0;
            #pragma unroll
            for (int e = 0; e < 8; ++e) s += Mp[(size_t)e * 14336 + gi];
            M2[gi] = s;
        }
    } else {
        int g = t >> 3, li = t & 7;
        if (g < NOUTC) {
            const float* wo = (g < 26) ? (pred_w + g * HD) : ex_w;
            float a = 0;
            for (int e = li; e < HD; e += 8) a += pe2_b[e] * wo[e];
            a += __shfl_down(a, 4, 8);
            a += __shfl_down(a, 2, 8);
            a += __shfl_down(a, 1, 8);
            if (li == 0) cb[g] = a + ((g < 26) ? pred_b[g] : ex_b[0]);
        }
    }
}

// ---------------------------------------------------------------------------
// Pair head: out[p,k] = gelu(S+O+C).M[:,k] + cb[k]. C (2 partials + pe1_b)
// staged in LDS. grid = 16*5*6.
// ---------------------------------------------------------------------------
__global__ __launch_bounds__(256) void k_pair(
    const float* __restrict__ SO, const float* __restrict__ cpb,
    const float* __restrict__ pe1_b,
    const float* __restrict__ M2, const float* __restrict__ cb,
    float* __restrict__ out)
{
    int blk = blockIdx.x;
    int bf = blk / 6, pt = blk % 6;
    int b = bf / FH, f = bf % FH;
    int t = threadIdx.x;
    int rl = t & 63, ks = t >> 6;
    __shared__ float Cs[HD];
    for (int d = t; d < HD; d += 256) {
        size_t o_ = (size_t)(b * FH + f) * HD + d;
        Cs[d] = cpb[o_] + cpb[40960 + o_] + pe1_b[d];
    }
    __syncthreads();
    int p = pt * 64 + rl;
    bool act = (p < NP);
    int i = 0, j = 0;
    if (act) { i = p / 19; int j0 = p % 19; j = j0 + (j0 >= i ? 1 : 0); }
    const float* Sr = SO + (size_t)(b * NO + i) * 1024;
    const float* Or = SO + (size_t)(b * NO + j) * 1024 + 512;
    float acc[NOUTC];
    #pragma unroll
    for (int k = 0; k < NOUTC; ++k) acc[k] = 0.f;
    if (act) {
        int d0 = ks * 128;
        for (int dd = 0; dd < 128; dd += 4) {
            int d = d0 + dd;
            float4 sv = *(const float4*)(Sr + d);
            float4 ov = *(const float4*)(Or + d);
            float4 cv = *(const float4*)(Cs + d);
            float g0 = gelu_f(sv.x + ov.x + cv.x);
            float g1 = gelu_f(sv.y + ov.y + cv.y);
            float g2 = gelu_f(sv.z + ov.z + cv.z);
            float g3 = gelu_f(sv.w + ov.w + cv.w);
            const float* m0 = M2 + d * 28;   // uniform -> s_load
            #pragma unroll
            for (int k = 0; k < NOUTC; ++k)
                acc[k] += g0 * m0[k] + g1 * m0[28 + k] + g2 * m0[56 + k] + g3 * m0[84 + k];
        }
    }
    __shared__ float red[4][64][NOUTC];
    #pragma unroll
    for (int k = 0; k < NOUTC; ++k) red[ks][rl][k] = acc[k];
    __syncthreads();
    int pbase = (b * FH + f) * NP;
    for (int idx = t; idx < 64 * NOUTC; idx += 256) {
        int r2 = idx / NOUTC, k = idx % NOUTC;
        int p2 = pt * 64 + r2;
        if (p2 >= NP) continue;
        float s = red[0][r2][k] + red[1][r2][k] + red[2][r2][k] + red[3][r2][k] + cb[k];
        if (k < 26) out[(size_t)(pbase + p2) * 26 + k] = s;
        else        out[PRED_N + pbase + p2] = s;
    }
}

// ---------------------------------------------------------------------------
extern "C" void kernel_launch(void* const* d_in, const int* in_sizes, int n_in,
                              void* d_out, int out_size, void* d_ws, size_t ws_size,
                              hipStream_t stream) {
    const float* temporal = (const float*)d_in[0];
    const float* objf     = (const float*)d_in[1];
    const float* fq       = (const float*)d_in[2];
    const float* sa_in_w  = (const float*)d_in[3];
    const float* sa_in_b  = (const float*)d_in[4];
    const float* sa_out_w = (const float*)d_in[5];
    const float* sa_out_b = (const float*)d_in[6];
    const float* ca_in_w  = (const float*)d_in[7];
    const float* ca_in_b  = (const float*)d_in[8];
    const float* ca_out_w = (const float*)d_in[9];
    const float* ca_out_b = (const float*)d_in[10];
    const float* ff1_w    = (const float*)d_in[11];
    const float* ff1_b    = (const float*)d_in[12];
    const float* ff2_w    = (const float*)d_in[13];
    const float* ff2_b    = (const float*)d_in[14];
    const float* n1_w     = (const float*)d_in[15];
    const float* n1_b     = (const float*)d_in[16];
    const float* n2_w     = (const float*)d_in[17];
    const float* n2_b     = (const float*)d_in[18];
    const float* n3_w     = (const float*)d_in[19];
    const float* n3_b     = (const float*)d_in[20];
    const float* norm_w   = (const float*)d_in[21];
    const float* norm_b   = (const float*)d_in[22];
    const float* pe1_w    = (const float*)d_in[23];
    const float* pe1_b    = (const float*)d_in[24];
    const float* pe2_w    = (const float*)d_in[25];
    const float* pe2_b    = (const float*)d_in[26];
    const float* pred_w   = (const float*)d_in[27];
    const float* pred_b   = (const float*)d_in[28];
    const float* ex_w     = (const float*)d_in[29];
    const float* ex_b     = (const float*)d_in[30];

    // ---- workspace layout (floats), total 1,284,128 fl ~= 5.14 MB ----
    float* ws  = (float*)d_ws;
    float* x   = ws;                  // 40960
    float* xn  = ws + 40960;          // 40960
    float* ao  = ws + 81920;          // 40960
    float* big = ws + 122880;         // 327680 (qkvp / ffp / Mp / qp / cpb)
    float* kvb = ws + 450560;         // 327680 (current layer: 2z x 160 x 1024)
    float* SO  = ws + 778240;         // 327680 (320 rows x [S(512)|O(512)])
    float* yp  = ws + 1105920;        // 163840 (up to 4 z-partials x 80 x 512)
    float* M2  = ws + 1269760;        // 14336
    float* cb  = ws + 1284096;        // 32
    float* out = (float*)d_out;

    // ---- prep: S / O projections (pe1_w is 512 rows x 1536 cols!) ----
    k_gemm<<<dim3(4, 20, 1), 256, 0, stream>>>(
        objf, HD, 0, nullptr, 0, pe1_w, 1536, SO, 1024, 512, 0);
    k_gemm<<<dim3(4, 20, 1), 256, 0, stream>>>(
        objf, HD, 0, nullptr, 0, pe1_w + 512, 1536, SO + 512, 1024, 512, 0);
    k_mpart<<<16, 256, 0, stream>>>(pe2_w, pred_w, ex_w, big);
    k_mcomb<<<3, 256, 0, stream>>>(big, pe2_b, pred_w, pred_b, ex_w, ex_b, M2, cb);

    // ---- transformer layers ----
    for (int l = 0; l < 2; ++l) {
        // CA K/V for this layer (1024 rows of ca_in_w starting at row 512)
        k_gemm<<<dim3(8, 10, 2), 256, 0, stream>>>(
            temporal, HD, 0, nullptr, 0,
            ca_in_w + (size_t)(l * 3 * HD + HD) * HD, HD,
            kvb, 1024, 256, 163840);
        // SA QKV
        k_gemm<<<dim3(12, 5, 2), 256, 0, stream>>>(
            (l == 0 ? fq : x), HD, (l == 0 ? 2 : 0), nullptr, 0,
            sa_in_w + (size_t)l * 3 * HD * HD, HD,
            big, 1536, 256, 122880);
        k_attn_sa<<<128, 256, 0, stream>>>(l, big, 122880, sa_in_b, ao);
        k_gemm<<<dim3(4, 5, 2), 256, 0, stream>>>(
            ao, HD, 0, nullptr, 0,
            sa_out_w + (size_t)l * HD * HD, HD, yp, HD, 256, 40960);
        k_resln<<<80, 256, 0, stream>>>(yp, 2, 40960, sa_out_b + l * HD,
            n1_w + l * HD, n1_b + l * HD,
            (l == 0 ? fq : x), (l == 0 ? FH : 0), x, 0, nullptr, nullptr, nullptr);
        // CA (Q rows are the first 512 rows of ca_in_w)
        k_gemm<<<dim3(4, 5, 2), 256, 0, stream>>>(
            x, HD, 0, nullptr, 0,
            ca_in_w + (size_t)l * 3 * HD * HD, HD, big, HD, 256, 40960);
        k_attn_ca<<<128, 256, 0, stream>>>(l, big, 40960, kvb, 163840, ca_in_b, ao);
        k_gemm<<<dim3(4, 5, 2), 256, 0, stream>>>(
            ao, HD, 0, nullptr, 0,
            ca_out_w + (size_t)l * HD * HD, HD, yp, HD, 256, 40960);
        k_resln<<<80, 256, 0, stream>>>(yp, 2, 40960, ca_out_b + l * HD,
            n2_w + l * HD, n2_b + l * HD, x, 0, x, 0, nullptr, nullptr, nullptr);
        // FF
        k_gemm<<<dim3(16, 5, 2), 256, 0, stream>>>(
            x, HD, 0, nullptr, 0,
            ff1_w + (size_t)l * FFD * HD, HD, big, FFD, 256, 163840);
        k_gemm<<<dim3(4, 5, 4), 256, 0, stream>>>(
            big, FFD, 1, ff1_b + l * FFD, 163840,
            ff2_w + (size_t)l * HD * FFD, FFD, yp, HD, 512, 40960);
        k_resln<<<80, 256, 0, stream>>>(yp, 4, 40960, ff2_b + l * HD,
            n3_w + l * HD, n3_b + l * HD, x, 0, x,
            (l == 1 ? 1 : 0), norm_w, norm_b, xn);
    }

    // ---- ctx projection (pe1_w cols [1024,1536)) + pair head ----
    k_gemm<<<dim3(4, 5, 2), 256, 0, stream>>>(
        xn, HD, 0, nullptr, 0, pe1_w + 1024, 1536, big, HD, 256, 40960);
    k_pair<<<480, 256, 0, stream>>>(SO, big, pe1_b, M2, cb, out);
}

// Round 4
// 510.301 us; speedup vs baseline: 1.4668x; 1.0701x over previous
//
#include <hip/hip_runtime.h>
#include <math.h>

// Problem sizes (fixed): H=512, heads=8, dh=64, L=2, FF=2048, B=16,
// Fh=5, Tmem=10, Nobj=20, Pairs=380, out = 26 pred + 1 ex.
#define HD 512
#define FFD 2048
#define NBATCH 16
#define FH 5
#define TM 10
#define NO 20
#define NP 380
#define NOUTC 27
#define PRED_N 790400   // 16*5*380*26

#define XM_PLAIN 0
#define XM_GELU  1
#define XM_FQ    2
#define XM_LN    3
#define XM_LN2   4

__device__ __forceinline__ float gelu_f(float v) {
    return 0.5f * v * (1.0f + erff(v * 0.70710678118654752440f));
}

// ---------------------------------------------------------------------------
// Generic tiled GEMM with fused prologues.
//   Y[z] (+=k-chunk z) or Y[z] (dual-weight z) = Xeff @ W^T
// Block tile: RT rows x 128 cols (RT=16 normally, RT=8 for LN modes).
// K-chunk 64. Thread tile: RT16 -> 2 rows x 4 strided cols; RT8 -> 1 x 4.
// Wt staged transposed, stride 129 (stores 2-way free, reads conflict-free).
// Prologues:
//   XM_PLAIN: Xeff = X[r]
//   XM_FQ   : Xeff = X[r % FH]
//   XM_GELU : Xeff = gelu(X[r] + X[r + gps] + bo[k])            (per-chunk)
//   XM_LN   : Xeff = LN(X[rr] + bo + sum_z parts[z]) (lw,lb); write xout
//   XM_LN2  : same + second LN (fw,fb)                          (full-row)
// zmode: 0 = z splits K (kbase=z*Klen); 1 = z selects W (+z*wzoff), full K.
// ---------------------------------------------------------------------------
__global__ __launch_bounds__(256) void k_gemm(
    const float* __restrict__ X, int ldx, int xmode,
    const float* __restrict__ parts, int np, int pzstr,
    const float* __restrict__ bo,
    const float* __restrict__ lw, const float* __restrict__ lb,
    const float* __restrict__ fw, const float* __restrict__ fb,
    float* __restrict__ xout, int xmod, int gps,
    const float* __restrict__ W, int ldw, int wzoff,
    float* __restrict__ Y, int N, int ldy, int zyoff,
    int Klen, int zmode)
{
    __shared__ float Wt[64 * 129];   // 33 KB
    __shared__ float Xs[4096];       // 16 KB: Xc(16x64) or Xf(8x512)
    int t = threadIdx.x;
    int nb = blockIdx.x * 128;
    int z  = blockIdx.z;
    int rt = (xmode >= XM_LN) ? 8 : 16;
    int r0 = blockIdx.y * rt;
    int kbase = (zmode == 0) ? z * Klen : 0;
    const float* Wb = W + (zmode == 1 ? (size_t)z * wzoff : 0);
    float* Yb = Y + (size_t)z * zyoff;
    int c  = t & 31;
    int rg = t >> 5;
    int sc = t >> 4;        // staging row 0..15
    int q  = t & 15;        // staging float4 idx

    // ---- LN prologue: full-row prestage with LayerNorm ----
    if (xmode >= XM_LN) {
        int rl = t >> 5;                 // 0..7
        int r  = r0 + rl;
        int c0 = (t & 31) * 16;
        int rr = xmod ? (r % xmod) : r;
        float v[16];
        #pragma unroll
        for (int u = 0; u < 16; u += 4) {
            float4 a = *(const float4*)(X + (size_t)rr * ldx + c0 + u);
            float4 bb = *(const float4*)(bo + c0 + u);
            float vx = a.x + bb.x, vy = a.y + bb.y, vz = a.z + bb.z, vw = a.w + bb.w;
            for (int zz = 0; zz < np; ++zz) {
                float4 p = *(const float4*)(parts + (size_t)zz * pzstr + (size_t)r * HD + c0 + u);
                vx += p.x; vy += p.y; vz += p.z; vw += p.w;
            }
            v[u] = vx; v[u + 1] = vy; v[u + 2] = vz; v[u + 3] = vw;
        }
        float s1 = 0, s2 = 0;
        #pragma unroll
        for (int u = 0; u < 16; ++u) { s1 += v[u]; s2 += v[u] * v[u]; }
        #pragma unroll
        for (int o = 16; o > 0; o >>= 1) {
            s1 += __shfl_down(s1, o, 32);
            s2 += __shfl_down(s2, o, 32);
        }
        s1 = __shfl(s1, 0, 32); s2 = __shfl(s2, 0, 32);
        float mean = s1 * (1.0f / HD);
        float rstd = rsqrtf(s2 * (1.0f / HD) - mean * mean + 1e-5f);
        #pragma unroll
        for (int u = 0; u < 16; ++u)
            v[u] = (v[u] - mean) * rstd * lw[c0 + u] + lb[c0 + u];
        if (xout && z == 0 && blockIdx.x == 0) {
            #pragma unroll
            for (int u = 0; u < 16; u += 4)
                *(float4*)(xout + (size_t)r * HD + c0 + u) =
                    make_float4(v[u], v[u + 1], v[u + 2], v[u + 3]);
        }
        if (xmode == XM_LN2) {
            float t1 = 0, t2 = 0;
            #pragma unroll
            for (int u = 0; u < 16; ++u) { t1 += v[u]; t2 += v[u] * v[u]; }
            #pragma unroll
            for (int o = 16; o > 0; o >>= 1) {
                t1 += __shfl_down(t1, o, 32);
                t2 += __shfl_down(t2, o, 32);
            }
            t1 = __shfl(t1, 0, 32); t2 = __shfl(t2, 0, 32);
            float m2 = t1 * (1.0f / HD);
            float rs2 = rsqrtf(t2 * (1.0f / HD) - m2 * m2 + 1e-5f);
            #pragma unroll
            for (int u = 0; u < 16; ++u)
                v[u] = (v[u] - m2) * rs2 * fw[c0 + u] + fb[c0 + u];
        }
        #pragma unroll
        for (int u = 0; u < 16; u += 4)
            *(float4*)(Xs + rl * HD + c0 + u) =
                make_float4(v[u], v[u + 1], v[u + 2], v[u + 3]);
        __syncthreads();
    }

    float a00 = 0, a01 = 0, a02 = 0, a03 = 0;
    float a10 = 0, a11 = 0, a12 = 0, a13 = 0;

    for (int kc = 0; kc < Klen; kc += 64) {
        int kg = kbase + kc;
        // ---- stage X chunk (non-LN modes) ----
        if (xmode <= XM_FQ) {
            float4 xv;
            if (xmode == XM_PLAIN) {
                xv = *(const float4*)(X + (size_t)(r0 + sc) * ldx + kg + q * 4);
            } else if (xmode == XM_FQ) {
                xv = *(const float4*)(X + (size_t)((r0 + sc) % FH) * ldx + kg + q * 4);
            } else {
                const float* p0 = X + (size_t)(r0 + sc) * ldx + kg + q * 4;
                float4 a = *(const float4*)p0;
                float4 b = *(const float4*)(p0 + gps);
                float4 bi = *(const float4*)(bo + kg + q * 4);
                xv.x = gelu_f(a.x + b.x + bi.x);
                xv.y = gelu_f(a.y + b.y + bi.y);
                xv.z = gelu_f(a.z + b.z + bi.z);
                xv.w = gelu_f(a.w + b.w + bi.w);
            }
            *(float4*)&Xs[sc * 64 + q * 4] = xv;
        }
        // ---- stage W tile transposed ----
        #pragma unroll
        for (int p = 0; p < 8; ++p) {
            int cc = sc + p * 16;
            float4 wv = *(const float4*)(Wb + (size_t)(nb + cc) * ldw + kg + q * 4);
            Wt[(q * 4 + 0) * 129 + cc] = wv.x;
            Wt[(q * 4 + 1) * 129 + cc] = wv.y;
            Wt[(q * 4 + 2) * 129 + cc] = wv.z;
            Wt[(q * 4 + 3) * 129 + cc] = wv.w;
        }
        __syncthreads();
        // ---- compute ----
        if (rt == 16) {
            const float* xr0 = &Xs[(rg * 2 + 0) * 64];
            const float* xr1 = &Xs[(rg * 2 + 1) * 64];
            #pragma unroll
            for (int k4 = 0; k4 < 16; ++k4) {
                float4 x0 = *(const float4*)(xr0 + k4 * 4);
                float4 x1 = *(const float4*)(xr1 + k4 * 4);
                const float* x0p = (const float*)&x0;
                const float* x1p = (const float*)&x1;
                #pragma unroll
                for (int i = 0; i < 4; ++i) {
                    const float* wrow = &Wt[(k4 * 4 + i) * 129 + c];
                    float w0 = wrow[0], w1 = wrow[32], w2 = wrow[64], w3 = wrow[96];
                    float xi0 = x0p[i], xi1 = x1p[i];
                    a00 = fmaf(xi0, w0, a00); a01 = fmaf(xi0, w1, a01);
                    a02 = fmaf(xi0, w2, a02); a03 = fmaf(xi0, w3, a03);
                    a10 = fmaf(xi1, w0, a10); a11 = fmaf(xi1, w1, a11);
                    a12 = fmaf(xi1, w2, a12); a13 = fmaf(xi1, w3, a13);
                }
            }
        } else {
            const float* xr0 = &Xs[rg * HD + kg];
            #pragma unroll
            for (int k4 = 0; k4 < 16; ++k4) {
                float4 x0 = *(const float4*)(xr0 + k4 * 4);
                const float* x0p = (const float*)&x0;
                #pragma unroll
                for (int i = 0; i < 4; ++i) {
                    const float* wrow = &Wt[(k4 * 4 + i) * 129 + c];
                    float xi0 = x0p[i];
                    a00 = fmaf(xi0, wrow[0],  a00);
                    a01 = fmaf(xi0, wrow[32], a01);
                    a02 = fmaf(xi0, wrow[64], a02);
                    a03 = fmaf(xi0, wrow[96], a03);
                }
            }
        }
        __syncthreads();
    }
    if (rt == 16) {
        float* yr = Yb + (size_t)(r0 + rg * 2) * ldy + nb + c;
        yr[0] = a00; yr[32] = a01; yr[64] = a02; yr[96] = a03;
        yr += ldy;
        yr[0] = a10; yr[32] = a11; yr[64] = a12; yr[96] = a13;
    } else {
        float* yr = Yb + (size_t)(r0 + rg) * ldy + nb + c;
        yr[0] = a00; yr[32] = a01; yr[64] = a02; yr[96] = a03;
    }
}

// ---------------------------------------------------------------------------
// Self-attention core: QKV partials (2 k-splits) + bias, softmax, AV.
// ---------------------------------------------------------------------------
__global__ __launch_bounds__(256) void k_attn_sa(
    int l, const float* __restrict__ qkvp, int zstr,
    const float* __restrict__ in_b, float* __restrict__ ao)
{
    int b = blockIdx.x >> 3, h = blockIdx.x & 7, t = threadIdx.x;
    __shared__ float qkv[3][FH][64];
    __shared__ float sc[FH][FH];
    __shared__ float aw[FH][FH];
    for (int idx = t; idx < 3 * FH * 64; idx += 256) {
        int m = idx / (FH * 64);
        int rem = idx % (FH * 64);
        int tok = rem >> 6, d = rem & 63;
        int col = m * HD + h * 64 + d;
        size_t o_ = (size_t)(b * FH + tok) * 1536 + col;
        qkv[m][tok][d] = qkvp[o_] + qkvp[zstr + o_] + in_b[l * 1536 + col];
    }
    __syncthreads();
    if (t < 25) {
        int tq = t / 5, tu = t % 5;
        float s = 0;
        for (int d = 0; d < 64; ++d) s += qkv[0][tq][d] * qkv[1][tu][d];
        sc[tq][tu] = s * 0.125f;
    }
    __syncthreads();
    if (t < 5) {
        float mx = -1e30f;
        for (int u = 0; u < 5; ++u) mx = fmaxf(mx, sc[t][u]);
        float e[5], sm = 0;
        for (int u = 0; u < 5; ++u) { e[u] = expf(sc[t][u] - mx); sm += e[u]; }
        for (int u = 0; u < 5; ++u) aw[t][u] = e[u] / sm;
    }
    __syncthreads();
    if (t < 64) {
        for (int tok = 0; tok < FH; ++tok) {
            float o = 0;
            for (int u = 0; u < 5; ++u) o += aw[tok][u] * qkv[2][u][t];
            ao[(size_t)(b * FH + tok) * HD + h * 64 + t] = o;
        }
    }
}

// ---------------------------------------------------------------------------
// Cross-attention core: Q partials (2) + bias; KV full (single) + bias.
// ---------------------------------------------------------------------------
__global__ __launch_bounds__(256) void k_attn_ca(
    int l, const float* __restrict__ qp, int qzstr,
    const float* __restrict__ kvl,
    const float* __restrict__ ca_in_b, float* __restrict__ ao)
{
    int b = blockIdx.x >> 3, h = blockIdx.x & 7, t = threadIdx.x;
    __shared__ float q[FH][64];
    __shared__ float kl[TM][64];
    __shared__ float vl[TM][64];
    __shared__ float sc[FH][TM];
    __shared__ float aw[FH][TM];
    const float* bb = ca_in_b + l * 1536;
    for (int idx = t; idx < FH * 64; idx += 256) {
        int tok = idx >> 6, d = idx & 63;
        size_t o_ = (size_t)(b * FH + tok) * HD + h * 64 + d;
        q[tok][d] = qp[o_] + qp[qzstr + o_] + bb[h * 64 + d];
    }
    for (int idx = t; idx < TM * 64; idx += 256) {
        int u = idx >> 6, d = idx & 63;
        size_t o_ = (size_t)(b * TM + u) * 1024 + h * 64 + d;
        kl[u][d] = kvl[o_] + bb[HD + h * 64 + d];
        vl[u][d] = kvl[o_ + 512] + bb[2 * HD + h * 64 + d];
    }
    __syncthreads();
    if (t < 50) {
        int tq = t / TM, tu = t % TM;
        float s = 0;
        for (int d = 0; d < 64; ++d) s += q[tq][d] * kl[tu][d];
        sc[tq][tu] = s * 0.125f;
    }
    __syncthreads();
    if (t < 5) {
        float mx = -1e30f;
        for (int u = 0; u < TM; ++u) mx = fmaxf(mx, sc[t][u]);
        float e[TM], sm = 0;
        for (int u = 0; u < TM; ++u) { e[u] = expf(sc[t][u] - mx); sm += e[u]; }
        for (int u = 0; u < TM; ++u) aw[t][u] = e[u] / sm;
    }
    __syncthreads();
    if (t < 64) {
        for (int tok = 0; tok < FH; ++tok) {
            float o = 0;
            for (int u = 0; u < TM; ++u) o += aw[tok][u] * vl[u][t];
            ao[(size_t)(b * FH + tok) * HD + h * 64 + t] = o;
        }
    }
}

// ---------------------------------------------------------------------------
// M = pe2^T @ [pred;ex]^T (blocks 0..15) + combined bias cb (block 16).
// ---------------------------------------------------------------------------
__global__ __launch_bounds__(256) void k_mfull(
    const float* __restrict__ pe2_w, const float* __restrict__ pe2_b,
    const float* __restrict__ pred_w, const float* __restrict__ pred_b,
    const float* __restrict__ ex_w, const float* __restrict__ ex_b,
    float* __restrict__ M2, float* __restrict__ cb)
{
    __shared__ float red[8 * 32 * NOUTC];
    int blk = blockIdx.x, t = threadIdx.x;
    if (blk < 16) {
        int dl = t & 31, ec = t >> 5;
        int d = blk * 32 + dl;
        float acc[NOUTC];
        #pragma unroll
        for (int k = 0; k < NOUTC; ++k) acc[k] = 0.f;
        for (int e = ec * 64; e < ec * 64 + 64; ++e) {
            float wv = pe2_w[(size_t)e * HD + d];
            #pragma unroll
            for (int k = 0; k < 26; ++k) acc[k] = fmaf(wv, pred_w[k * HD + e], acc[k]);
            acc[26] = fmaf(wv, ex_w[e], acc[26]);
        }
        #pragma unroll
        for (int k = 0; k < NOUTC; ++k) red[(ec * 32 + dl) * NOUTC + k] = acc[k];
        __syncthreads();
        for (int idx = t; idx < 32 * NOUTC; idx += 256) {
            int dl2 = idx / NOUTC, k = idx % NOUTC;
            float s = 0;
            #pragma unroll
            for (int e = 0; e < 8; ++e) s += red[(e * 32 + dl2) * NOUTC + k];
            M2[(size_t)(blk * 32 + dl2) * 28 + k] = s;
        }
    } else {
        int g = t >> 3, li = t & 7;
        if (g < NOUTC) {
            const float* wo = (g < 26) ? (pred_w + g * HD) : ex_w;
            float a = 0;
            for (int e = li; e < HD; e += 8) a += pe2_b[e] * wo[e];
            a += __shfl_down(a, 4, 8);
            a += __shfl_down(a, 2, 8);
            a += __shfl_down(a, 1, 8);
            if (li == 0) cb[g] = a + ((g < 26) ? pred_b[g] : ex_b[0]);
        }
    }
}

// ---------------------------------------------------------------------------
// Pair head, LDS-staged: stage <=5 S rows, 20 O rows, combined C row into
// LDS (pad 516 per row), compute from LDS, alias red[] over staging buffer.
// grid = 16*5*6.
// ---------------------------------------------------------------------------
__global__ __launch_bounds__(256) void k_pair(
    const float* __restrict__ SO, const float* __restrict__ cpb,
    const float* __restrict__ pe1_b,
    const float* __restrict__ M2, const float* __restrict__ cb,
    float* __restrict__ out)
{
    __shared__ float sh[26 * 516];   // 53.7 KB; red aliases after compute
    int blk = blockIdx.x;
    int bf = blk / 6, pt = blk % 6;
    int b = bf / FH, f = bf % FH;
    int t = threadIdx.x;
    int rl = t & 63, ks = t >> 6;
    int i0 = (pt * 64) / 19;
    // ---- stage ----
    for (int idx = t; idx < 26 * 128; idx += 256) {
        int row = idx >> 7, c4 = (idx & 127) << 2;
        float4 v;
        if (row < 5) {
            int i = i0 + row; if (i > 19) i = 19;
            v = *(const float4*)(SO + (size_t)(b * NO + i) * 1024 + c4);
        } else if (row < 25) {
            int j = row - 5;
            v = *(const float4*)(SO + (size_t)(b * NO + j) * 1024 + 512 + c4);
        } else {
            size_t o_ = (size_t)(b * FH + f) * HD + c4;
            float4 p0 = *(const float4*)(cpb + o_);
            float4 p1 = *(const float4*)(cpb + 40960 + o_);
            float4 pb = *(const float4*)(pe1_b + c4);
            v.x = p0.x + p1.x + pb.x;
            v.y = p0.y + p1.y + pb.y;
            v.z = p0.z + p1.z + pb.z;
            v.w = p0.w + p1.w + pb.w;
        }
        *(float4*)(sh + row * 516 + c4) = v;
    }
    __syncthreads();
    int p = pt * 64 + rl;
    bool act = (p < NP);
    int i = 0, j = 0;
    if (act) { i = p / 19; int j0 = p % 19; j = j0 + (j0 >= i ? 1 : 0); }
    const float* Sr = sh + (size_t)(i - i0) * 516;
    const float* Or = sh + (size_t)(5 + j) * 516;
    const float* Cr = sh + 25 * 516;
    float acc[NOUTC];
    #pragma unroll
    for (int k = 0; k < NOUTC; ++k) acc[k] = 0.f;
    if (act) {
        int d0 = ks * 128;
        for (int dd = 0; dd < 128; dd += 4) {
            int d = d0 + dd;
            float4 sv = *(const float4*)(Sr + d);
            float4 ov = *(const float4*)(Or + d);
            float4 cv = *(const float4*)(Cr + d);
            float g0 = gelu_f(sv.x + ov.x + cv.x);
            float g1 = gelu_f(sv.y + ov.y + cv.y);
            float g2 = gelu_f(sv.z + ov.z + cv.z);
            float g3 = gelu_f(sv.w + ov.w + cv.w);
            const float* m0 = M2 + (size_t)d * 28;   // wave-uniform -> s_load
            #pragma unroll
            for (int k = 0; k < NOUTC; ++k)
                acc[k] += g0 * m0[k] + g1 * m0[28 + k] + g2 * m0[56 + k] + g3 * m0[84 + k];
        }
    }
    __syncthreads();                 // all staging reads complete
    float* red = sh;                 // alias
    #pragma unroll
    for (int k = 0; k < NOUTC; ++k) red[(ks * 64 + rl) * NOUTC + k] = acc[k];
    __syncthreads();
    int pbase = (b * FH + f) * NP;
    for (int idx = t; idx < 64 * NOUTC; idx += 256) {
        int r2 = idx / NOUTC, k = idx % NOUTC;
        int p2 = pt * 64 + r2;
        if (p2 >= NP) continue;
        float s = red[(0 * 64 + r2) * NOUTC + k] + red[(1 * 64 + r2) * NOUTC + k]
                + red[(2 * 64 + r2) * NOUTC + k] + red[(3 * 64 + r2) * NOUTC + k] + cb[k];
        if (k < 26) out[(size_t)(pbase + p2) * 26 + k] = s;
        else        out[PRED_N + pbase + p2] = s;
    }
}

// ---------------------------------------------------------------------------
extern "C" void kernel_launch(void* const* d_in, const int* in_sizes, int n_in,
                              void* d_out, int out_size, void* d_ws, size_t ws_size,
                              hipStream_t stream) {
    const float* temporal = (const float*)d_in[0];
    const float* objf     = (const float*)d_in[1];
    const float* fq       = (const float*)d_in[2];
    const float* sa_in_w  = (const float*)d_in[3];
    const float* sa_in_b  = (const float*)d_in[4];
    const float* sa_out_w = (const float*)d_in[5];
    const float* sa_out_b = (const float*)d_in[6];
    const float* ca_in_w  = (const float*)d_in[7];
    const float* ca_in_b  = (const float*)d_in[8];
    const float* ca_out_w = (const float*)d_in[9];
    const float* ca_out_b = (const float*)d_in[10];
    const float* ff1_w    = (const float*)d_in[11];
    const float* ff1_b    = (const float*)d_in[12];
    const float* ff2_w    = (const float*)d_in[13];
    const float* ff2_b    = (const float*)d_in[14];
    const float* n1_w     = (const float*)d_in[15];
    const float* n1_b     = (const float*)d_in[16];
    const float* n2_w     = (const float*)d_in[17];
    const float* n2_b     = (const float*)d_in[18];
    const float* n3_w     = (const float*)d_in[19];
    const float* n3_b     = (const float*)d_in[20];
    const float* norm_w   = (const float*)d_in[21];
    const float* norm_b   = (const float*)d_in[22];
    const float* pe1_w    = (const float*)d_in[23];
    const float* pe1_b    = (const float*)d_in[24];
    const float* pe2_w    = (const float*)d_in[25];
    const float* pe2_b    = (const float*)d_in[26];
    const float* pred_w   = (const float*)d_in[27];
    const float* pred_b   = (const float*)d_in[28];
    const float* ex_w     = (const float*)d_in[29];
    const float* ex_b     = (const float*)d_in[30];

    // ---- workspace (floats), total 1,284,128 ~= 5.14 MB ----
    float* ws  = (float*)d_ws;
    float* xa  = ws;                  // 40960
    float* xb  = ws + 40960;          // 40960
    float* ao  = ws + 81920;          // 40960
    float* big = ws + 122880;         // 327680 (qkvp / ffp / cpb)
    float* kvb = ws + 450560;         // 327680 ([l][b*10+u][1024])
    float* SO  = ws + 778240;         // 327680 (320 x [S|O])
    float* yp  = ws + 1105920;        // 163840 (up to 4 partials x 80 x 512)
    float* M2  = ws + 1269760;        // 14336
    float* cb  = ws + 1284096;        // 32
    float* out = (float*)d_out;

    // ---- prep: S/O (dual-z), M, CA K/V both layers (dual-z) ----
    k_gemm<<<dim3(4, 20, 2), 256, 0, stream>>>(
        objf, HD, XM_PLAIN, nullptr, 0, 0, nullptr, nullptr, nullptr,
        nullptr, nullptr, nullptr, 0, 0,
        pe1_w, 1536, 512, SO, 512, 1024, 512, 512, 1);
    k_mfull<<<17, 256, 0, stream>>>(pe2_w, pe2_b, pred_w, pred_b, ex_w, ex_b, M2, cb);
    k_gemm<<<dim3(8, 10, 2), 256, 0, stream>>>(
        temporal, HD, XM_PLAIN, nullptr, 0, 0, nullptr, nullptr, nullptr,
        nullptr, nullptr, nullptr, 0, 0,
        ca_in_w + 262144, HD, 786432, kvb, 1024, 1024, 163840, 512, 1);

    for (int l = 0; l < 2; ++l) {
        // SA QKV
        if (l == 0) {
            k_gemm<<<dim3(12, 5, 2), 256, 0, stream>>>(
                fq, HD, XM_FQ, nullptr, 0, 0, nullptr, nullptr, nullptr,
                nullptr, nullptr, nullptr, 0, 0,
                sa_in_w, HD, 0, big, 1536, 1536, 122880, 256, 0);
        } else {
            // prologue: x3 = LN(x2 + ff2(l0) partials + ff2_b0; n3_0), write xa
            k_gemm<<<dim3(12, 10, 2), 256, 0, stream>>>(
                xb, HD, XM_LN, yp, 4, 40960, ff2_b, n3_w, n3_b,
                nullptr, nullptr, xa, 0, 0,
                sa_in_w + 786432, HD, 0, big, 1536, 1536, 122880, 256, 0);
        }
        k_attn_sa<<<128, 256, 0, stream>>>(l, big, 122880, sa_in_b, ao);
        k_gemm<<<dim3(4, 5, 2), 256, 0, stream>>>(
            ao, HD, XM_PLAIN, nullptr, 0, 0, nullptr, nullptr, nullptr,
            nullptr, nullptr, nullptr, 0, 0,
            sa_out_w + (size_t)l * 262144, HD, 0, yp, HD, HD, 40960, 256, 0);
        // CA Q, prologue: x1 = LN(res + saproj + b; n1), write xa(l0)/xb(l1)
        k_gemm<<<dim3(4, 10, 2), 256, 0, stream>>>(
            (l == 0 ? fq : xa), HD, XM_LN, yp, 2, 40960,
            sa_out_b + l * HD, n1_w + l * HD, n1_b + l * HD,
            nullptr, nullptr, (l == 0 ? xa : xb), (l == 0 ? FH : 0), 0,
            ca_in_w + (size_t)l * 786432, HD, 0, big, HD, HD, 40960, 256, 0);
        k_attn_ca<<<128, 256, 0, stream>>>(l, big, 40960, kvb + (size_t)l * 163840,
                                           ca_in_b, ao);
        k_gemm<<<dim3(4, 5, 2), 256, 0, stream>>>(
            ao, HD, XM_PLAIN, nullptr, 0, 0, nullptr, nullptr, nullptr,
            nullptr, nullptr, nullptr, 0, 0,
            ca_out_w + (size_t)l * 262144, HD, 0, yp, HD, HD, 40960, 256, 0);
        // FF1, prologue: x2 = LN(x1 + caproj + b; n2), write xb(l0)/xa(l1)
        k_gemm<<<dim3(16, 10, 2), 256, 0, stream>>>(
            (l == 0 ? xa : xb), HD, XM_LN, yp, 2, 40960,
            ca_out_b + l * HD, n2_w + l * HD, n2_b + l * HD,
            nullptr, nullptr, (l == 0 ? xb : xa), 0, 0,
            ff1_w + (size_t)l * 1048576, HD, 0, big, FFD, FFD, 163840, 256, 0);
        // FF2 (gelu combine in staging)
        k_gemm<<<dim3(4, 5, 4), 256, 0, stream>>>(
            big, FFD, XM_GELU, nullptr, 0, 0, ff1_b + l * FFD, nullptr, nullptr,
            nullptr, nullptr, nullptr, 0, 163840,
            ff2_w + (size_t)l * 1048576, FFD, 0, yp, HD, HD, 40960, 512, 0);
    }

    // normc: prologue resln(x5 + ff2(l1) + b; n3_1) then final LN, project ctx
    k_gemm<<<dim3(4, 10, 2), 256, 0, stream>>>(
        xa, HD, XM_LN2, yp, 4, 40960, ff2_b + HD, n3_w + HD, n3_b + HD,
        norm_w, norm_b, nullptr, 0, 0,
        pe1_w + 1024, 1536, 0, big, HD, HD, 40960, 256, 0);
    k_pair<<<480, 256, 0, stream>>>(SO, big, pe1_b, M2, cb, out);
}